// Round 1
// baseline (203.197 us; speedup 1.0000x reference)
//
#include <hip/hip_runtime.h>

// ---------------------------------------------------------------------------
// MultiHeadAttentionLayer fused kernel, MI355X (gfx950)
//
// Algebraic rearrangement (exact in f32):
//   score_l  = (q_h^T A + g) . k_lh / 8        A = Wq^T Wk, g = Wk^T bq
//              (the per-(q,h) constant terms are softmax-invariant; bk drops)
//   vbar_h   = sum_l softmax(score)_l * v_lh   (sum p = 1 folds bv into b2)
//   out      = vbar_flat @ Wo2T + b2           Wo2T[i][j] = sum_d Wo[j][h(i)*64+d] * Wv[d][i&63]
//                                              b2[j] = bo[j] + sum_i Wo[j][i]*bv[i&63]
// ---------------------------------------------------------------------------

#define NFEAT 512
#define NHEAD 8
#define DHEAD 64
#define LWIN  16
#define MPOS  16          // (b,t) positions per block
#define LDSP  20          // vbarT pitch (floats): 16B-aligned b128, odd-ish bank spread

__device__ __forceinline__ float lanebcast(float x, int l) {
    return __uint_as_float(__builtin_amdgcn_readlane(__float_as_uint(x), l));
}

// ---- precompute A (64x64), g (64), b2 (512) -------------------------------
__global__ void precompute_small(const float* __restrict__ Wq, const float* __restrict__ bq,
                                 const float* __restrict__ Wk,
                                 const float* __restrict__ Wo, const float* __restrict__ bo,
                                 const float* __restrict__ bv,
                                 float* __restrict__ A, float* __restrict__ g,
                                 float* __restrict__ b2) {
    int idx = blockIdx.x * 256 + threadIdx.x;
    if (idx < 4096) {                       // A[d][d'] = sum_e Wq[e][d] * Wk[e][d']
        int d = idx >> 6, dp = idx & 63;
        float s = 0.f;
        #pragma unroll 8
        for (int e = 0; e < 64; ++e) s = fmaf(Wq[e * 64 + d], Wk[e * 64 + dp], s);
        A[idx] = s;
    } else if (idx < 4160) {                // g[d'] = sum_e Wk[e][d'] * bq[e]
        int dp = idx - 4096;
        float s = 0.f;
        #pragma unroll 8
        for (int e = 0; e < 64; ++e) s = fmaf(Wk[e * 64 + dp], bq[e], s);
        g[dp] = s;
    } else if (idx < 4672) {                // b2[j] = bo[j] + sum_i Wo[j][i]*bv[i&63]
        int j = idx - 4160;
        float s = bo[j];
        #pragma unroll 8
        for (int i = 0; i < 512; ++i) s = fmaf(Wo[j * 512 + i], bv[i & 63], s);
        b2[j] = s;
    }
}

// ---- precompute Wo2T (512x512): Wo2T[i][j] = sum_d Wo[j][ (i>>6)*64+d ] * Wv[d][ i&63 ]
__global__ void precompute_wo2(const float* __restrict__ Wo, const float* __restrict__ Wv,
                               float* __restrict__ Wo2T) {
    int idx = blockIdx.x * 256 + threadIdx.x;   // 262144 total
    int i = idx & 511, j = idx >> 9;
    int h = i >> 6, e = i & 63;
    float s = 0.f;
    #pragma unroll 8
    for (int d = 0; d < 64; ++d)
        s = fmaf(Wo[j * 512 + h * 64 + d], Wv[d * 64 + e], s);
    Wo2T[(size_t)i * 512 + j] = s;
}

// ---- main fused kernel -----------------------------------------------------
__global__ __launch_bounds__(512, 4)
void attn_main(const float* __restrict__ q, const float* __restrict__ k,
               const float* __restrict__ v,
               const float* __restrict__ A, const float* __restrict__ g,
               const float* __restrict__ b2, const float* __restrict__ Wo2T,
               float* __restrict__ out) {
    __shared__ __align__(16) float vbarT[NFEAT * LDSP];

    const int tid  = threadIdx.x;
    const int lane = tid & 63;
    const int fe   = tid;                 // feature index 0..511 (wave = head)
    const int bt0  = blockIdx.x * MPOS;

    // A column for this lane (d' = lane), shared across heads/positions
    float Areg[64];
    #pragma unroll
    for (int d = 0; d < 64; ++d) Areg[d] = A[d * 64 + lane];
    const float greg = g[lane];

    // ---------------- phase 1: attention -> vbar staged in LDS -------------
    for (int p = 0; p < MPOS; ++p) {
        const int bt = bt0 + p;
        const float qv = q[(size_t)bt * NFEAT + fe];

        // w[lane] = (sum_d q_h[d] * A[d][lane] + g[lane]) * (1/sqrt(64))
        float w = greg;
        #pragma unroll
        for (int d = 0; d < 64; ++d)
            w = fmaf(lanebcast(qv, d), Areg[d], w);
        w *= 0.125f;

        // scores: per l, wave-reduce( w * k[l][head*64+lane] )
        const float* kp = k + (size_t)bt * (LWIN * NFEAT) + fe;
        float kv[LWIN];
        #pragma unroll
        for (int l = 0; l < LWIN; ++l) kv[l] = kp[(size_t)l * NFEAT];
        float sc[LWIN];
        #pragma unroll
        for (int l = 0; l < LWIN; ++l) sc[l] = w * kv[l];
        #pragma unroll
        for (int m = 1; m < 64; m <<= 1) {
            #pragma unroll
            for (int l = 0; l < LWIN; ++l) sc[l] += __shfl_xor(sc[l], m, 64);
        }

        // softmax over L=16 (replicated in every lane of the wave)
        float mx = sc[0];
        #pragma unroll
        for (int l = 1; l < LWIN; ++l) mx = fmaxf(mx, sc[l]);
        float sum = 0.f;
        #pragma unroll
        for (int l = 0; l < LWIN; ++l) { sc[l] = __expf(sc[l] - mx); sum += sc[l]; }
        const float inv = 1.0f / sum;

        // vbar[fe] = (sum_l e_l * v[l][fe]) * inv
        const float* vp = v + (size_t)bt * (LWIN * NFEAT) + fe;
        float vb = 0.f;
        #pragma unroll
        for (int l = 0; l < LWIN; ++l) vb = fmaf(sc[l], vp[(size_t)l * NFEAT], vb);
        vbarT[fe * LDSP + p] = vb * inv;
    }
    __syncthreads();

    // ---------------- phase 2: out = vbar @ Wo2T + b2 ----------------------
    // thread owns 8 positions (half) x 2 consecutive j
    const int ph = tid >> 8;             // 0 or 1 (wave-uniform)
    const int j0 = (tid & 255) * 2;

    float acc[8][2];
    #pragma unroll
    for (int pp = 0; pp < 8; ++pp) { acc[pp][0] = 0.f; acc[pp][1] = 0.f; }

    #pragma unroll 4
    for (int i = 0; i < NFEAT; ++i) {
        const float2 wo = *reinterpret_cast<const float2*>(&Wo2T[(size_t)i * 512 + j0]);
        const float4 va = *reinterpret_cast<const float4*>(&vbarT[i * LDSP + ph * 8]);
        const float4 vbq = *reinterpret_cast<const float4*>(&vbarT[i * LDSP + ph * 8 + 4]);
        const float vv0 = va.x, vv1 = va.y, vv2 = va.z, vv3 = va.w;
        const float vv4 = vbq.x, vv5 = vbq.y, vv6 = vbq.z, vv7 = vbq.w;
        acc[0][0] = fmaf(vv0, wo.x, acc[0][0]); acc[0][1] = fmaf(vv0, wo.y, acc[0][1]);
        acc[1][0] = fmaf(vv1, wo.x, acc[1][0]); acc[1][1] = fmaf(vv1, wo.y, acc[1][1]);
        acc[2][0] = fmaf(vv2, wo.x, acc[2][0]); acc[2][1] = fmaf(vv2, wo.y, acc[2][1]);
        acc[3][0] = fmaf(vv3, wo.x, acc[3][0]); acc[3][1] = fmaf(vv3, wo.y, acc[3][1]);
        acc[4][0] = fmaf(vv4, wo.x, acc[4][0]); acc[4][1] = fmaf(vv4, wo.y, acc[4][1]);
        acc[5][0] = fmaf(vv5, wo.x, acc[5][0]); acc[5][1] = fmaf(vv5, wo.y, acc[5][1]);
        acc[6][0] = fmaf(vv6, wo.x, acc[6][0]); acc[6][1] = fmaf(vv6, wo.y, acc[6][1]);
        acc[7][0] = fmaf(vv7, wo.x, acc[7][0]); acc[7][1] = fmaf(vv7, wo.y, acc[7][1]);
    }

    const float b20 = b2[j0], b21 = b2[j0 + 1];
    #pragma unroll
    for (int pp = 0; pp < 8; ++pp) {
        const int bt = bt0 + ph * 8 + pp;
        float2 o;
        o.x = acc[pp][0] + b20;
        o.y = acc[pp][1] + b21;
        *reinterpret_cast<float2*>(&out[(size_t)bt * NFEAT + j0]) = o;
    }
}

// ---------------------------------------------------------------------------
extern "C" void kernel_launch(void* const* d_in, const int* in_sizes, int n_in,
                              void* d_out, int out_size, void* d_ws, size_t ws_size,
                              hipStream_t stream) {
    const float* q  = (const float*)d_in[0];
    const float* k  = (const float*)d_in[1];
    const float* v  = (const float*)d_in[2];
    const float* Wq = (const float*)d_in[3];
    const float* bq = (const float*)d_in[4];
    const float* Wk = (const float*)d_in[5];
    // d_in[6] = bk: provably unused (softmax-invariant constant)
    const float* Wv = (const float*)d_in[7];
    const float* bv = (const float*)d_in[8];
    const float* Wo = (const float*)d_in[9];
    const float* bo = (const float*)d_in[10];
    float* out = (float*)d_out;

    float* ws   = (float*)d_ws;
    float* A    = ws;            // 4096 floats
    float* g    = ws + 4096;     // 64
    float* b2   = ws + 4160;     // 512
    float* Wo2T = ws + 4672;     // 262144  (total ~1.02 MB of d_ws)

    const int BT = in_sizes[0] / NFEAT;      // B*T = 8192

    hipLaunchKernelGGL(precompute_small, dim3(19), dim3(256), 0, stream,
                       Wq, bq, Wk, Wo, bo, bv, A, g, b2);
    hipLaunchKernelGGL(precompute_wo2, dim3(1024), dim3(256), 0, stream,
                       Wo, Wv, Wo2T);
    hipLaunchKernelGGL(attn_main, dim3(BT / MPOS), dim3(512), 0, stream,
                       q, k, v, A, g, b2, Wo2T, out);
}